// Round 6
// baseline (142.570 us; speedup 1.0000x reference)
//
#include <hip/hip_runtime.h>
#include <math.h>

#define B_N 65536
#define C_N 100
constexpr float ALPHA = 0.01f;
constexpr float TAU   = 2.0f;
constexpr float TEMP  = 2.0f;
constexpr float EPSF  = 1e-9f;
constexpr float NEG_SENT = -1.0e30f;   // sentinel: exp -> 0, finite

// ---------------- DPP reduction helpers (VALU-only) ----------------
// After rowsum32, all lanes with (lane&31)>=16 hold the 32-group total.
template<int CTRL>
__device__ __forceinline__ float fadd_dpp(float x) {
    return x + __int_as_float(__builtin_amdgcn_update_dpp(
        0, __float_as_int(x), CTRL, 0xF, 0xF, true));
}
__device__ __forceinline__ float rowsum32(float x) {
    x = fadd_dpp<0xB1>(x);    // quad_perm xor1
    x = fadd_dpp<0x4E>(x);    // quad_perm xor2
    x = fadd_dpp<0x124>(x);   // row_ror:4
    x = fadd_dpp<0x128>(x);   // row_ror:8
    x = fadd_dpp<0x142>(x);   // row_bcast15
    return x;
}
template<int CTRL>
__device__ __forceinline__ void amax_dpp(unsigned &hi, unsigned &lo) {
    const unsigned yh = (unsigned)__builtin_amdgcn_update_dpp(0, (int)hi, CTRL, 0xF, 0xF, true);
    const unsigned yl = (unsigned)__builtin_amdgcn_update_dpp(0, (int)lo, CTRL, 0xF, 0xF, true);
    const bool take = (yh > hi) || (yh == hi && yl > lo);
    hi = take ? yh : hi;
    lo = take ? yl : lo;
}
__device__ __forceinline__ void rowamax32(unsigned &hi, unsigned &lo) {
    amax_dpp<0xB1>(hi, lo);
    amax_dpp<0x4E>(hi, lo);
    amax_dpp<0x124>(hi, lo);
    amax_dpp<0x128>(hi, lo);
    amax_dpp<0x142>(hi, lo);
}

__device__ __forceinline__ float wsum(float v) {
    #pragma unroll
    for (int o = 32; o; o >>= 1) v += __shfl_xor(v, o);
    return v;
}

// ---------- prep: bincount (0-255) + prior (256) + cos softmax (257-260) ----------
__global__ void prep_k(const float* __restrict__ cosf, const float* __restrict__ prior,
                       const int* __restrict__ target,
                       float* __restrict__ sm, float* __restrict__ lp, float* __restrict__ c3,
                       int* __restrict__ counts) {
    const int b = blockIdx.x;
    if (b < 256) {
        __shared__ int h[C_N];
        for (int i = threadIdx.x; i < C_N; i += blockDim.x) h[i] = 0;
        __syncthreads();
        const int gid = b * blockDim.x + threadIdx.x;
        const int stride = 256 * blockDim.x;
        for (int i = gid; i < B_N; i += stride) atomicAdd(&h[target[i]], 1);
        __syncthreads();
        for (int i = threadIdx.x; i < C_N; i += blockDim.x)
            if (h[i]) atomicAdd(&counts[i], h[i]);
    } else if (b == 256) {
        __shared__ float sp[C_N];
        __shared__ float val[C_N];
        const int t = threadIdx.x;
        if (t < C_N) sp[t] = prior[t];
        __syncthreads();
        int rank = 0;
        float lpi = 0.f;
        if (t < C_N) {
            const float pi = sp[t];
            for (int j = 0; j < C_N; ++j) {
                const float pj = sp[j];
                rank += (pj < pi) || (pj == pi && j < t);   // stable argsort rank
            }
            val[rank] = pi;
            lpi = __logf(pi + EPSF);
            lp[t] = lpi;
        }
        __syncthreads();
        if (t < C_N) {
            const float inv = val[C_N - 1 - rank];
            c3[t] = lpi - TAU * __logf(inv + EPSF);
        }
    } else {
        const int gw = (b - 257) * 4 + (threadIdx.x >> 6);   // 0..15
        const int lane = threadIdx.x & 63;
        for (int row = gw; row < C_N; row += 16) {
            const float* rp = cosf + row * C_N;
            const float v0 = rp[lane];
            const bool has1 = (lane + 64) < C_N;
            const float v1 = has1 ? rp[lane + 64] : -INFINITY;
            float m = fmaxf(v0, v1);
            #pragma unroll
            for (int o = 32; o; o >>= 1) m = fmaxf(m, __shfl_xor(m, o));
            const float e0 = __expf(v0 - m);
            const float e1 = has1 ? __expf(v1 - m) : 0.f;
            const float s = wsum(e0 + e1);
            const float is = 1.0f / s;
            sm[row * C_N + lane] = e0 * is;
            if (has1) sm[row * C_N + lane + 64] = e1 * is;
        }
    }
}

// ---------- main: 512 chunky blocks (2/CU, statically resident) ----------
#define NBLK 512
#define WPB 16                          // waves per block (1024 threads)
#define PAIRS 4                         // row-pairs per wave; 512*16*4*2 = 65536 rows

__launch_bounds__(1024, 8)
__global__ void main_k(const int* __restrict__ target,
                       const float* __restrict__ e1p, const float* __restrict__ e2p,
                       const float* __restrict__ e3p, const float* __restrict__ opp,
                       const float* __restrict__ outp,
                       const float* __restrict__ sm, const float* __restrict__ lp,
                       const float* __restrict__ c3, const int* __restrict__ counts,
                       float* __restrict__ dout,
                       float* __restrict__ ploss, float* __restrict__ pkl, float* __restrict__ pn) {
    const int t    = threadIdx.x;
    const int lane = t & 63;
    const int gl   = lane & 31;
    const int half = lane >> 5;
    const int wslot = t >> 6;            // 0..15
    const bool act = gl < 25;
    const int c0 = 4 * gl;

    __shared__ __align__(16) float s_rcp[104];
    __shared__ __align__(16) float s_lp[104];
    __shared__ __align__(16) float s_c3[104];
    __shared__ float bl[WPB], bk[WPB], bn[WPB];

    if (t < C_N) {
        s_rcp[t] = 1.0f / (float)counts[t];   // precise div, once per class per block
        s_lp[t]  = lp[t];
        s_c3[t]  = c3[t];
    }
    __syncthreads();

    float4 LP = make_float4(0,0,0,0), CO = make_float4(0,0,0,0);
    if (act) {
        LP = *(const float4*)(s_lp + c0);
        CO = *(const float4*)(s_c3 + c0);
    }

    const int pair0 = blockIdx.x * (WPB * PAIRS) + wslot * PAIRS;

    // prefetch targets + rcp for all 4 pairs
    int tg[PAIRS];
    #pragma unroll
    for (int q = 0; q < PAIRS; ++q) tg[q] = target[2 * (pair0 + q) + half];
    float rcq[PAIRS];
    #pragma unroll
    for (int q = 0; q < PAIRS; ++q) rcq[q] = s_rcp[tg[q]];

    float lossA = 0.f, klA = 0.f, nA = 0.f;
    float esv[PAIRS][4];

    #pragma unroll 1
    for (int q = 0; q < PAIRS; ++q) {
        const int row = 2 * (pair0 + q) + half;
        const int tgt = tg[q];
        const float rc = rcq[q];
        const int base = row * C_N;

        float4 E1, E2, E3, OP, OU, SM;
        E1 = E2 = E3 = OP = OU = make_float4(NEG_SENT, NEG_SENT, NEG_SENT, NEG_SENT);
        SM = make_float4(0,0,0,0);
        if (act) {
            E1 = *(const float4*)(e1p + base + c0);
            E2 = *(const float4*)(e2p + base + c0);
            E3 = *(const float4*)(e3p + base + c0);
            OP = *(const float4*)(opp + base + c0);
            OU = *(const float4*)(outp + base + c0);
            SM = *(const float4*)(sm + tgt * C_N + c0);
        }

        // soft labels
        const float la0 = (1.0f - ALPHA) * (c0     == tgt) + ALPHA * SM.x;
        const float la1 = (1.0f - ALPHA) * (c0 + 1 == tgt) + ALPHA * SM.y;
        const float la2 = (1.0f - ALPHA) * (c0 + 2 == tgt) + ALPHA * SM.z;
        const float la3 = (1.0f - ALPHA) * (c0 + 3 == tgt) + ALPHA * SM.w;

        const float l20 = E2.x + LP.x, l21 = E2.y + LP.y, l22 = E2.z + LP.z, l23 = E2.w + LP.w;
        const float l30 = E3.x + CO.x, l31 = E3.y + CO.y, l32 = E3.z + CO.z, l33 = E3.w + CO.w;

        // partition functions, no max shift (|real logits| <= ~19; sentinel -> exp = 0)
        float s1 = __expf(E1.x) + __expf(E1.y) + __expf(E1.z) + __expf(E1.w);
        float s2 = __expf(l20) + __expf(l21) + __expf(l22) + __expf(l23);
        float s3 = __expf(l30) + __expf(l31) + __expf(l32) + __expf(l33);
        float dt = la0 * (E1.x + l20 + l30) + la1 * (E1.y + l21 + l31)
                 + la2 * (E1.z + l22 + l32) + la3 * (E1.w + l23 + l33);

        // teacher probs at m=0
        const float a0 = OP.x * 0.5f, a1 = OP.y * 0.5f, a2 = OP.z * 0.5f, a3 = OP.w * 0.5f;
        const float p0 = __expf(a0), p1 = __expf(a1), p2 = __expf(a2), p3 = __expf(a3);
        float zt = p0 + p1 + p2 + p3;

        // local argmax candidate (first-index tiebreak); sentinel never wins
        float bv = OP.x; int bi = c0;
        if (OP.y > bv) { bv = OP.y; bi = c0 + 1; }
        if (OP.z > bv) { bv = OP.z; bi = c0 + 2; }
        if (OP.w > bv) { bv = OP.w; bi = c0 + 3; }
        unsigned bb = __float_as_uint(bv);
        bb = ((int)bb < 0) ? ~bb : (bb | 0x80000000u);
        unsigned khi = bb, klo = (unsigned)~bi;

        // student
        const float es0 = OU.x * rc, es1 = OU.y * rc, es2 = OU.z * rc, es3 = OU.w * rc;
        const float x0 = es0 * 0.5f, x1 = es1 * 0.5f, x2 = es2 * 0.5f, x3 = es3 * 0.5f;
        float zs = __expf(x0) + __expf(x1) + __expf(x2) + __expf(x3);
        float D  = p0 * (a0 - x0) + p1 * (a1 - x1) + p2 * (a2 - x2) + p3 * (a3 - x3);

        // DPP reductions; results valid on lanes with (lane&31)>=16
        s1 = rowsum32(s1);
        s2 = rowsum32(s2);
        s3 = rowsum32(s3);
        dt = rowsum32(dt);
        zt = rowsum32(zt);
        zs = rowsum32(zs);
        D  = rowsum32(D);
        rowamax32(khi, klo);

        const float ce  = __logf(s1 * s2 * s3) - dt;
        const int   mi  = (int)~klo;
        const float rzt = 1.0f / zt;
        const float kl  = D * rzt + __logf(zs * rzt);
        const bool  own = (gl == 16);
        const bool  sel = own && (mi == tgt);

        lossA += own ? ce : 0.f;
        klA   += sel ? kl : 0.f;
        nA    += sel ? 1.f : 0.f;

        esv[q][0] = es0; esv[q][1] = es1; esv[q][2] = es2; esv[q][3] = es3;
    }

    // wave combine: owner lanes 16 (half 0) and 48 (half 1)
    const float lossW = __shfl(lossA, 16) + __shfl(lossA, 48);
    const float klW   = __shfl(klA, 16) + __shfl(klA, 48);
    const float nW    = __shfl(nA, 16) + __shfl(nA, 48);

    if (lane == 0) { bl[wslot] = lossW; bk[wslot] = klW; bn[wslot] = nW; }
    __syncthreads();   // vmcnt drain cheap: no outstanding stores yet
    if (t == 0) {
        float L = 0.f, K = 0.f, N = 0.f;
        #pragma unroll
        for (int i = 0; i < WPB; ++i) { L += bl[i]; K += bk[i]; N += bn[i]; }
        ploss[blockIdx.x] = L; pkl[blockIdx.x] = K; pn[blockIdx.x] = N;
    }

    // all dout stores last (no barrier after -> no store-ack drain)
    if (act) {
        #pragma unroll
        for (int q = 0; q < PAIRS; ++q) {
            const int base = (2 * (pair0 + q) + half) * C_N;
            *(float2*)(dout + 2 + base + c0)     = make_float2(esv[q][0], esv[q][1]);
            *(float2*)(dout + 2 + base + c0 + 2) = make_float2(esv[q][2], esv[q][3]);
        }
    }
}

// ---------- final reduction ----------
__global__ void final_k(const float* __restrict__ ploss, const float* __restrict__ pkl,
                        const float* __restrict__ pn, float* __restrict__ dout) {
    __shared__ float sl[256], sk[256], sn[256];
    const int t = threadIdx.x;
    float l = 0.f, k = 0.f, n = 0.f;
    for (int i = t; i < NBLK; i += 256) { l += ploss[i]; k += pkl[i]; n += pn[i]; }
    sl[t] = l; sk[t] = k; sn[t] = n;
    __syncthreads();
    for (int s = 128; s; s >>= 1) {
        if (t < s) { sl[t] += sl[t + s]; sk[t] += sk[t + s]; sn[t] += sn[t + s]; }
        __syncthreads();
    }
    if (t == 0) {
        dout[0] = sl[0] / (float)B_N;
        const float kl = (sn[0] > 0.f) ? (sk[0] / fmaxf(sn[0], 1.f)) : 0.f;
        dout[1] = kl * (TEMP * TEMP) * 3.0f;
    }
}

extern "C" void kernel_launch(void* const* d_in, const int* in_sizes, int n_in,
                              void* d_out, int out_size, void* d_ws, size_t ws_size,
                              hipStream_t stream) {
    const int*   target = (const int*)  d_in[1];
    const float* cosf   = (const float*)d_in[2];
    const float* oldp   = (const float*)d_in[3];
    const float* e1     = (const float*)d_in[4];
    const float* e2     = (const float*)d_in[5];
    const float* e3     = (const float*)d_in[6];
    const float* outp   = (const float*)d_in[7];
    const float* prior  = (const float*)d_in[8];

    float* ws    = (float*)d_ws;
    float* sm    = ws;                 // [10000]
    float* lp    = ws + 10000;         // [100]
    float* c3    = ws + 10100;         // [100]
    int*   cnts  = (int*)(ws + 10200); // [100]
    float* ploss = ws + 10304;         // [NBLK]
    float* pkl   = ploss + NBLK;       // [NBLK]
    float* pn    = pkl + NBLK;         // [NBLK]

    hipMemsetAsync(cnts, 0, C_N * sizeof(int), stream);
    prep_k<<<261, 256, 0, stream>>>(cosf, prior, target, sm, lp, c3, cnts);
    main_k<<<NBLK, 1024, 0, stream>>>(target, e1, e2, e3, oldp, outp,
                                      sm, lp, c3, cnts, (float*)d_out, ploss, pkl, pn);
    final_k<<<1, 256, 0, stream>>>(ploss, pkl, pn, (float*)d_out);
}

// Round 7
// 52.452 us; speedup vs baseline: 2.7181x; 2.7181x over previous
//
#include <hip/hip_runtime.h>
#include <math.h>

#define B_N 65536
#define C_N 100
constexpr float ALPHA = 0.01f;
constexpr float TAU   = 2.0f;
constexpr float TEMP  = 2.0f;
constexpr float EPSF  = 1e-9f;
constexpr float NEG_SENT = -1.0e30f;   // sentinel: exp -> 0, finite

// ---------------- DPP reduction helpers (VALU-only) ----------------
// After rowsum32, all lanes with (lane&31)>=16 hold the 32-group total.
template<int CTRL>
__device__ __forceinline__ float fadd_dpp(float x) {
    return x + __int_as_float(__builtin_amdgcn_update_dpp(
        0, __float_as_int(x), CTRL, 0xF, 0xF, true));
}
__device__ __forceinline__ float rowsum32(float x) {
    x = fadd_dpp<0xB1>(x);    // quad_perm xor1
    x = fadd_dpp<0x4E>(x);    // quad_perm xor2
    x = fadd_dpp<0x124>(x);   // row_ror:4
    x = fadd_dpp<0x128>(x);   // row_ror:8
    x = fadd_dpp<0x142>(x);   // row_bcast15
    return x;
}
template<int CTRL>
__device__ __forceinline__ void amax_dpp(unsigned &hi, unsigned &lo) {
    const unsigned yh = (unsigned)__builtin_amdgcn_update_dpp(0, (int)hi, CTRL, 0xF, 0xF, true);
    const unsigned yl = (unsigned)__builtin_amdgcn_update_dpp(0, (int)lo, CTRL, 0xF, 0xF, true);
    const bool take = (yh > hi) || (yh == hi && yl > lo);
    hi = take ? yh : hi;
    lo = take ? yl : lo;
}
__device__ __forceinline__ void rowamax32(unsigned &hi, unsigned &lo) {
    amax_dpp<0xB1>(hi, lo);
    amax_dpp<0x4E>(hi, lo);
    amax_dpp<0x124>(hi, lo);
    amax_dpp<0x128>(hi, lo);
    amax_dpp<0x142>(hi, lo);
}

__device__ __forceinline__ float wsum(float v) {
    #pragma unroll
    for (int o = 32; o; o >>= 1) v += __shfl_xor(v, o);
    return v;
}

// ---------- prep: bincount (0-255) + prior (256) + cos softmax (257-260) ----------
__global__ void prep_k(const float* __restrict__ cosf, const float* __restrict__ prior,
                       const int* __restrict__ target,
                       float* __restrict__ sm, float* __restrict__ lp, float* __restrict__ c3,
                       int* __restrict__ counts) {
    const int b = blockIdx.x;
    if (b < 256) {
        __shared__ int h[C_N];
        for (int i = threadIdx.x; i < C_N; i += blockDim.x) h[i] = 0;
        __syncthreads();
        const int gid = b * blockDim.x + threadIdx.x;
        const int stride = 256 * blockDim.x;
        for (int i = gid; i < B_N; i += stride) atomicAdd(&h[target[i]], 1);
        __syncthreads();
        for (int i = threadIdx.x; i < C_N; i += blockDim.x)
            if (h[i]) atomicAdd(&counts[i], h[i]);
    } else if (b == 256) {
        __shared__ float sp[C_N];
        __shared__ float val[C_N];
        const int t = threadIdx.x;
        if (t < C_N) sp[t] = prior[t];
        __syncthreads();
        int rank = 0;
        float lpi = 0.f;
        if (t < C_N) {
            const float pi = sp[t];
            for (int j = 0; j < C_N; ++j) {
                const float pj = sp[j];
                rank += (pj < pi) || (pj == pi && j < t);   // stable argsort rank
            }
            val[rank] = pi;
            lpi = __logf(pi + EPSF);
            lp[t] = lpi;
        }
        __syncthreads();
        if (t < C_N) {
            const float inv = val[C_N - 1 - rank];
            c3[t] = lpi - TAU * __logf(inv + EPSF);
        }
    } else {
        const int gw = (b - 257) * 4 + (threadIdx.x >> 6);   // 0..15
        const int lane = threadIdx.x & 63;
        for (int row = gw; row < C_N; row += 16) {
            const float* rp = cosf + row * C_N;
            const float v0 = rp[lane];
            const bool has1 = (lane + 64) < C_N;
            const float v1 = has1 ? rp[lane + 64] : -INFINITY;
            float m = fmaxf(v0, v1);
            #pragma unroll
            for (int o = 32; o; o >>= 1) m = fmaxf(m, __shfl_xor(m, o));
            const float e0 = __expf(v0 - m);
            const float e1 = has1 ? __expf(v1 - m) : 0.f;
            const float s = wsum(e0 + e1);
            const float is = 1.0f / s;
            sm[row * C_N + lane] = e0 * is;
            if (has1) sm[row * C_N + lane + 64] = e1 * is;
        }
    }
}

// ---------- main: 2 independent row-pairs per wave (ILP-2), fully static ----------
#define NBLK 4096    // 4096 blocks * 4 waves * 4 rows = 65536

__launch_bounds__(256)
__global__ void main_k(const int* __restrict__ target,
                       const float* __restrict__ e1p, const float* __restrict__ e2p,
                       const float* __restrict__ e3p, const float* __restrict__ opp,
                       const float* __restrict__ outp,
                       const float* __restrict__ sm, const float* __restrict__ lp,
                       const float* __restrict__ c3, const int* __restrict__ counts,
                       float* __restrict__ dout,
                       float* __restrict__ ploss, float* __restrict__ pkl, float* __restrict__ pn) {
    const int lane = threadIdx.x & 63;
    const int gl   = lane & 31;
    const int half = lane >> 5;
    const int wslot = threadIdx.x >> 6;
    const int gw   = blockIdx.x * 4 + wslot;       // global wave id
    const bool act = gl < 25;
    const int c0 = 4 * gl;
    const bool own = (gl == 16);

    const int rowA = 4 * gw + half;                // pair A
    const int rowB = 4 * gw + 2 + half;            // pair B
    const int tgtA = target[rowA];
    const int tgtB = target[rowB];
    const int baseA = rowA * C_N;
    const int baseB = rowB * C_N;

    float4 LP = make_float4(0,0,0,0), CO = make_float4(0,0,0,0);
    float4 E1A, E2A, E3A, OPA, OUA, SMA, E1B, E2B, E3B, OPB, OUB, SMB;
    E1A = E2A = E3A = OPA = OUA = make_float4(NEG_SENT, NEG_SENT, NEG_SENT, NEG_SENT);
    E1B = E2B = E3B = OPB = OUB = make_float4(NEG_SENT, NEG_SENT, NEG_SENT, NEG_SENT);
    SMA = SMB = make_float4(0,0,0,0);
    if (act) {
        LP  = *(const float4*)(lp + c0);
        CO  = *(const float4*)(c3 + c0);
        E1A = *(const float4*)(e1p + baseA + c0);
        E1B = *(const float4*)(e1p + baseB + c0);
        E2A = *(const float4*)(e2p + baseA + c0);
        E2B = *(const float4*)(e2p + baseB + c0);
        E3A = *(const float4*)(e3p + baseA + c0);
        E3B = *(const float4*)(e3p + baseB + c0);
        OPA = *(const float4*)(opp + baseA + c0);
        OPB = *(const float4*)(opp + baseB + c0);
        OUA = *(const float4*)(outp + baseA + c0);
        OUB = *(const float4*)(outp + baseB + c0);
        SMA = *(const float4*)(sm + tgtA * C_N + c0);
        SMB = *(const float4*)(sm + tgtB * C_N + c0);
    }
    const float rcA = 1.0f / (float)counts[tgtA];
    const float rcB = 1.0f / (float)counts[tgtB];

    // ---------------- pair A compute ----------------
    const float laA0 = (1.0f - ALPHA) * (c0     == tgtA) + ALPHA * SMA.x;
    const float laA1 = (1.0f - ALPHA) * (c0 + 1 == tgtA) + ALPHA * SMA.y;
    const float laA2 = (1.0f - ALPHA) * (c0 + 2 == tgtA) + ALPHA * SMA.z;
    const float laA3 = (1.0f - ALPHA) * (c0 + 3 == tgtA) + ALPHA * SMA.w;
    const float lA20 = E2A.x + LP.x, lA21 = E2A.y + LP.y, lA22 = E2A.z + LP.z, lA23 = E2A.w + LP.w;
    const float lA30 = E3A.x + CO.x, lA31 = E3A.y + CO.y, lA32 = E3A.z + CO.z, lA33 = E3A.w + CO.w;
    float s1A = __expf(E1A.x) + __expf(E1A.y) + __expf(E1A.z) + __expf(E1A.w);
    float s2A = __expf(lA20) + __expf(lA21) + __expf(lA22) + __expf(lA23);
    float s3A = __expf(lA30) + __expf(lA31) + __expf(lA32) + __expf(lA33);
    float dtA = laA0 * (E1A.x + lA20 + lA30) + laA1 * (E1A.y + lA21 + lA31)
              + laA2 * (E1A.z + lA22 + lA32) + laA3 * (E1A.w + lA23 + lA33);
    const float aA0 = OPA.x * 0.5f, aA1 = OPA.y * 0.5f, aA2 = OPA.z * 0.5f, aA3 = OPA.w * 0.5f;
    const float pA0 = __expf(aA0), pA1 = __expf(aA1), pA2 = __expf(aA2), pA3 = __expf(aA3);
    float ztA = pA0 + pA1 + pA2 + pA3;
    float bvA = OPA.x; int biA = c0;
    if (OPA.y > bvA) { bvA = OPA.y; biA = c0 + 1; }
    if (OPA.z > bvA) { bvA = OPA.z; biA = c0 + 2; }
    if (OPA.w > bvA) { bvA = OPA.w; biA = c0 + 3; }
    unsigned bbA = __float_as_uint(bvA);
    bbA = ((int)bbA < 0) ? ~bbA : (bbA | 0x80000000u);
    unsigned khiA = bbA, kloA = (unsigned)~biA;
    const float esA0 = OUA.x * rcA, esA1 = OUA.y * rcA, esA2 = OUA.z * rcA, esA3 = OUA.w * rcA;
    const float xA0 = esA0 * 0.5f, xA1 = esA1 * 0.5f, xA2 = esA2 * 0.5f, xA3 = esA3 * 0.5f;
    float zsA = __expf(xA0) + __expf(xA1) + __expf(xA2) + __expf(xA3);
    float DA  = pA0 * (aA0 - xA0) + pA1 * (aA1 - xA1) + pA2 * (aA2 - xA2) + pA3 * (aA3 - xA3);
    if (act) {
        *(float2*)(dout + 2 + baseA + c0)     = make_float2(esA0, esA1);
        *(float2*)(dout + 2 + baseA + c0 + 2) = make_float2(esA2, esA3);
    }

    // ---------------- pair B compute ----------------
    const float laB0 = (1.0f - ALPHA) * (c0     == tgtB) + ALPHA * SMB.x;
    const float laB1 = (1.0f - ALPHA) * (c0 + 1 == tgtB) + ALPHA * SMB.y;
    const float laB2 = (1.0f - ALPHA) * (c0 + 2 == tgtB) + ALPHA * SMB.z;
    const float laB3 = (1.0f - ALPHA) * (c0 + 3 == tgtB) + ALPHA * SMB.w;
    const float lB20 = E2B.x + LP.x, lB21 = E2B.y + LP.y, lB22 = E2B.z + LP.z, lB23 = E2B.w + LP.w;
    const float lB30 = E3B.x + CO.x, lB31 = E3B.y + CO.y, lB32 = E3B.z + CO.z, lB33 = E3B.w + CO.w;
    float s1B = __expf(E1B.x) + __expf(E1B.y) + __expf(E1B.z) + __expf(E1B.w);
    float s2B = __expf(lB20) + __expf(lB21) + __expf(lB22) + __expf(lB23);
    float s3B = __expf(lB30) + __expf(lB31) + __expf(lB32) + __expf(lB33);
    float dtB = laB0 * (E1B.x + lB20 + lB30) + laB1 * (E1B.y + lB21 + lB31)
              + laB2 * (E1B.z + lB22 + lB32) + laB3 * (E1B.w + lB23 + lB33);
    const float aB0 = OPB.x * 0.5f, aB1 = OPB.y * 0.5f, aB2 = OPB.z * 0.5f, aB3 = OPB.w * 0.5f;
    const float pB0 = __expf(aB0), pB1 = __expf(aB1), pB2 = __expf(aB2), pB3 = __expf(aB3);
    float ztB = pB0 + pB1 + pB2 + pB3;
    float bvB = OPB.x; int biB = c0;
    if (OPB.y > bvB) { bvB = OPB.y; biB = c0 + 1; }
    if (OPB.z > bvB) { bvB = OPB.z; biB = c0 + 2; }
    if (OPB.w > bvB) { bvB = OPB.w; biB = c0 + 3; }
    unsigned bbB = __float_as_uint(bvB);
    bbB = ((int)bbB < 0) ? ~bbB : (bbB | 0x80000000u);
    unsigned khiB = bbB, kloB = (unsigned)~biB;
    const float esB0 = OUB.x * rcB, esB1 = OUB.y * rcB, esB2 = OUB.z * rcB, esB3 = OUB.w * rcB;
    const float xB0 = esB0 * 0.5f, xB1 = esB1 * 0.5f, xB2 = esB2 * 0.5f, xB3 = esB3 * 0.5f;
    float zsB = __expf(xB0) + __expf(xB1) + __expf(xB2) + __expf(xB3);
    float DB  = pB0 * (aB0 - xB0) + pB1 * (aB1 - xB1) + pB2 * (aB2 - xB2) + pB3 * (aB3 - xB3);
    if (act) {
        *(float2*)(dout + 2 + baseB + c0)     = make_float2(esB0, esB1);
        *(float2*)(dout + 2 + baseB + c0 + 2) = make_float2(esB2, esB3);
    }

    // ---------------- interleaved DPP reductions (A/B chains overlap) ----------------
    s1A = rowsum32(s1A);  s1B = rowsum32(s1B);
    s2A = rowsum32(s2A);  s2B = rowsum32(s2B);
    s3A = rowsum32(s3A);  s3B = rowsum32(s3B);
    dtA = rowsum32(dtA);  dtB = rowsum32(dtB);
    ztA = rowsum32(ztA);  ztB = rowsum32(ztB);
    zsA = rowsum32(zsA);  zsB = rowsum32(zsB);
    DA  = rowsum32(DA);   DB  = rowsum32(DB);
    rowamax32(khiA, kloA);
    rowamax32(khiB, kloB);

    const float ceA = __logf(s1A * s2A * s3A) - dtA;
    const float ceB = __logf(s1B * s2B * s3B) - dtB;
    const int miA = (int)~kloA;
    const int miB = (int)~kloB;
    const float rztA = 1.0f / ztA, rztB = 1.0f / ztB;
    const float klvA = DA * rztA + __logf(zsA * rztA);
    const float klvB = DB * rztB + __logf(zsB * rztB);
    const bool selA = own && (miA == tgtA);
    const bool selB = own && (miB == tgtB);

    float lossAcc = own ? (ceA + ceB) : 0.f;
    float klAcc   = (selA ? klvA : 0.f) + (selB ? klvB : 0.f);
    float nAcc    = (selA ? 1.f : 0.f) + (selB ? 1.f : 0.f);

    // wave combine: owner lanes 16 (half 0) and 48 (half 1)
    const float lossW = __shfl(lossAcc, 16) + __shfl(lossAcc, 48);
    const float klW   = __shfl(klAcc, 16) + __shfl(klAcc, 48);
    const float nW    = __shfl(nAcc, 16) + __shfl(nAcc, 48);

    __shared__ float bl[4], bk[4], bn[4];
    if (lane == 0) { bl[wslot] = lossW; bk[wslot] = klW; bn[wslot] = nW; }
    __syncthreads();
    if (threadIdx.x == 0) {
        ploss[blockIdx.x] = bl[0] + bl[1] + bl[2] + bl[3];
        pkl[blockIdx.x]   = bk[0] + bk[1] + bk[2] + bk[3];
        pn[blockIdx.x]    = bn[0] + bn[1] + bn[2] + bn[3];
    }
}

// ---------- final reduction ----------
__global__ void final_k(const float* __restrict__ ploss, const float* __restrict__ pkl,
                        const float* __restrict__ pn, float* __restrict__ dout) {
    __shared__ float sl[256], sk[256], sn[256];
    const int t = threadIdx.x;
    float l = 0.f, k = 0.f, n = 0.f;
    for (int i = t; i < NBLK; i += 256) { l += ploss[i]; k += pkl[i]; n += pn[i]; }
    sl[t] = l; sk[t] = k; sn[t] = n;
    __syncthreads();
    for (int s = 128; s; s >>= 1) {
        if (t < s) { sl[t] += sl[t + s]; sk[t] += sk[t + s]; sn[t] += sn[t + s]; }
        __syncthreads();
    }
    if (t == 0) {
        dout[0] = sl[0] / (float)B_N;
        const float kl = (sn[0] > 0.f) ? (sk[0] / fmaxf(sn[0], 1.f)) : 0.f;
        dout[1] = kl * (TEMP * TEMP) * 3.0f;
    }
}

extern "C" void kernel_launch(void* const* d_in, const int* in_sizes, int n_in,
                              void* d_out, int out_size, void* d_ws, size_t ws_size,
                              hipStream_t stream) {
    const int*   target = (const int*)  d_in[1];
    const float* cosf   = (const float*)d_in[2];
    const float* oldp   = (const float*)d_in[3];
    const float* e1     = (const float*)d_in[4];
    const float* e2     = (const float*)d_in[5];
    const float* e3     = (const float*)d_in[6];
    const float* outp   = (const float*)d_in[7];
    const float* prior  = (const float*)d_in[8];

    float* ws    = (float*)d_ws;
    float* sm    = ws;                 // [10000]
    float* lp    = ws + 10000;         // [100]
    float* c3    = ws + 10100;         // [100]
    int*   cnts  = (int*)(ws + 10200); // [100]
    float* ploss = ws + 10304;         // [NBLK]
    float* pkl   = ploss + NBLK;       // [NBLK]
    float* pn    = pkl + NBLK;         // [NBLK]

    hipMemsetAsync(cnts, 0, C_N * sizeof(int), stream);
    prep_k<<<261, 256, 0, stream>>>(cosf, prior, target, sm, lp, c3, cnts);
    main_k<<<NBLK, 256, 0, stream>>>(target, e1, e2, e3, oldp, outp,
                                     sm, lp, c3, cnts, (float*)d_out, ploss, pkl, pn);
    final_k<<<1, 256, 0, stream>>>(ploss, pkl, pn, (float*)d_out);
}

// Round 8
// 51.788 us; speedup vs baseline: 2.7529x; 1.0128x over previous
//
#include <hip/hip_runtime.h>
#include <math.h>

#define B_N 65536
#define C_N 100
constexpr float ALPHA = 0.01f;
constexpr float TAU   = 2.0f;
constexpr float TEMP  = 2.0f;
constexpr float EPSF  = 1e-9f;
constexpr float NEG_SENT = -1.0e30f;   // sentinel: exp -> 0, finite

// ---------------- DPP reduction helpers (VALU-only) ----------------
// After rowsum32, all lanes with (lane&31)>=16 hold the 32-group total.
template<int CTRL>
__device__ __forceinline__ float fadd_dpp(float x) {
    return x + __int_as_float(__builtin_amdgcn_update_dpp(
        0, __float_as_int(x), CTRL, 0xF, 0xF, true));
}
__device__ __forceinline__ float rowsum32(float x) {
    x = fadd_dpp<0xB1>(x);    // quad_perm xor1
    x = fadd_dpp<0x4E>(x);    // quad_perm xor2
    x = fadd_dpp<0x124>(x);   // row_ror:4
    x = fadd_dpp<0x128>(x);   // row_ror:8
    x = fadd_dpp<0x142>(x);   // row_bcast15
    return x;
}
template<int CTRL>
__device__ __forceinline__ void amax_dpp(unsigned &hi, unsigned &lo) {
    const unsigned yh = (unsigned)__builtin_amdgcn_update_dpp(0, (int)hi, CTRL, 0xF, 0xF, true);
    const unsigned yl = (unsigned)__builtin_amdgcn_update_dpp(0, (int)lo, CTRL, 0xF, 0xF, true);
    const bool take = (yh > hi) || (yh == hi && yl > lo);
    hi = take ? yh : hi;
    lo = take ? yl : lo;
}
__device__ __forceinline__ void rowamax32(unsigned &hi, unsigned &lo) {
    amax_dpp<0xB1>(hi, lo);
    amax_dpp<0x4E>(hi, lo);
    amax_dpp<0x124>(hi, lo);
    amax_dpp<0x128>(hi, lo);
    amax_dpp<0x142>(hi, lo);
}

__device__ __forceinline__ float wsum(float v) {
    #pragma unroll
    for (int o = 32; o; o >>= 1) v += __shfl_xor(v, o);
    return v;
}

// ---------- prep: bincount (0-255) + prior tables (256) + cos softmax (257-260) ----------
__global__ void prep_k(const float* __restrict__ cosf, const float* __restrict__ prior,
                       const int* __restrict__ target,
                       float* __restrict__ sm, float* __restrict__ w2,
                       float* __restrict__ w3, float* __restrict__ Ht,
                       int* __restrict__ counts) {
    const int b = blockIdx.x;
    if (b < 256) {
        __shared__ int h[C_N];
        for (int i = threadIdx.x; i < C_N; i += blockDim.x) h[i] = 0;
        __syncthreads();
        const int gid = b * blockDim.x + threadIdx.x;
        const int stride = 256 * blockDim.x;
        for (int i = gid; i < B_N; i += stride) atomicAdd(&h[target[i]], 1);
        __syncthreads();
        for (int i = threadIdx.x; i < C_N; i += blockDim.x)
            if (h[i]) atomicAdd(&counts[i], h[i]);
    } else if (b == 256) {
        __shared__ float sp[C_N];
        __shared__ float val[C_N];
        const int t = threadIdx.x;
        if (t < C_N) sp[t] = prior[t];
        __syncthreads();
        int rank = 0;
        float lpi = 0.f, pi = 0.f;
        if (t < C_N) {
            pi = sp[t];
            for (int j = 0; j < C_N; ++j) {
                const float pj = sp[j];
                rank += (pj < pi) || (pj == pi && j < t);   // stable argsort rank
            }
            val[rank] = pi;
            lpi = __logf(pi + EPSF);
        }
        __syncthreads();
        if (t < C_N) {
            const float inv = val[C_N - 1 - rank];
            const float c3v = lpi - TAU * __logf(inv + EPSF);
            w2[t] = pi + EPSF;          // exp(e2+lp) = w2*exp(e2)
            w3[t] = __expf(c3v);        // exp(e3+c3) = w3*exp(e3)
            Ht[t] = lpi + c3v;          // lp+c3, for the label dot
        }
    } else {
        const int gw = (b - 257) * 4 + (threadIdx.x >> 6);   // 0..15
        const int lane = threadIdx.x & 63;
        for (int row = gw; row < C_N; row += 16) {
            const float* rp = cosf + row * C_N;
            const float v0 = rp[lane];
            const bool has1 = (lane + 64) < C_N;
            const float v1 = has1 ? rp[lane + 64] : -INFINITY;
            float m = fmaxf(v0, v1);
            #pragma unroll
            for (int o = 32; o; o >>= 1) m = fmaxf(m, __shfl_xor(m, o));
            const float e0 = __expf(v0 - m);
            const float e1 = has1 ? __expf(v1 - m) : 0.f;
            const float s = wsum(e0 + e1);
            const float is = 1.0f / s;
            sm[row * C_N + lane] = e0 * is;
            if (has1) sm[row * C_N + lane + 64] = e1 * is;
        }
    }
}

// ---------- main: role-split blocks. 0..4095 = CE (loss), 4096..8191 = KL+store ----------
#define HBLK 4096
#define NBLK (2 * HBLK)

__launch_bounds__(256)
__global__ void main_k(const int* __restrict__ target,
                       const float* __restrict__ e1p, const float* __restrict__ e2p,
                       const float* __restrict__ e3p, const float* __restrict__ opp,
                       const float* __restrict__ outp,
                       const float* __restrict__ sm, const float* __restrict__ w2p,
                       const float* __restrict__ w3p, const float* __restrict__ Hp,
                       const int* __restrict__ counts,
                       float* __restrict__ dout,
                       float* __restrict__ ploss, float* __restrict__ pkl, float* __restrict__ pn) {
    const int lane = threadIdx.x & 63;
    const int gl   = lane & 31;
    const int half = lane >> 5;
    const int wslot = threadIdx.x >> 6;
    const bool act = gl < 25;
    const int c0 = 4 * gl;
    const bool own = (gl == 16);
    __shared__ float bl[4], bk[4], bn[4];

    if (blockIdx.x < HBLK) {
        // ================= CE role: e1,e2,e3 + sm gather -> loss partial =================
        const int gw = blockIdx.x * 4 + wslot;
        const int rowA = 4 * gw + half;
        const int rowB = 4 * gw + 2 + half;
        const int tgtA = target[rowA];
        const int tgtB = target[rowB];
        const int baseA = rowA * C_N;
        const int baseB = rowB * C_N;

        float4 W2 = make_float4(0,0,0,0), W3 = make_float4(0,0,0,0), HH = make_float4(0,0,0,0);
        float4 E1A, E2A, E3A, E1B, E2B, E3B, SMA, SMB;
        E1A = E2A = E3A = E1B = E2B = E3B = make_float4(NEG_SENT, NEG_SENT, NEG_SENT, NEG_SENT);
        SMA = SMB = make_float4(0,0,0,0);
        if (act) {
            W2  = *(const float4*)(w2p + c0);
            W3  = *(const float4*)(w3p + c0);
            HH  = *(const float4*)(Hp + c0);
            E1A = *(const float4*)(e1p + baseA + c0);
            E1B = *(const float4*)(e1p + baseB + c0);
            E2A = *(const float4*)(e2p + baseA + c0);
            E2B = *(const float4*)(e2p + baseB + c0);
            E3A = *(const float4*)(e3p + baseA + c0);
            E3B = *(const float4*)(e3p + baseB + c0);
            SMA = *(const float4*)(sm + tgtA * C_N + c0);
            SMB = *(const float4*)(sm + tgtB * C_N + c0);
        }

        // pair A
        const float laA0 = (1.0f - ALPHA) * (c0     == tgtA) + ALPHA * SMA.x;
        const float laA1 = (1.0f - ALPHA) * (c0 + 1 == tgtA) + ALPHA * SMA.y;
        const float laA2 = (1.0f - ALPHA) * (c0 + 2 == tgtA) + ALPHA * SMA.z;
        const float laA3 = (1.0f - ALPHA) * (c0 + 3 == tgtA) + ALPHA * SMA.w;
        float s1A = __expf(E1A.x) + __expf(E1A.y) + __expf(E1A.z) + __expf(E1A.w);
        float s2A = W2.x * __expf(E2A.x) + W2.y * __expf(E2A.y)
                  + W2.z * __expf(E2A.z) + W2.w * __expf(E2A.w);
        float s3A = W3.x * __expf(E3A.x) + W3.y * __expf(E3A.y)
                  + W3.z * __expf(E3A.z) + W3.w * __expf(E3A.w);
        float dtA = laA0 * (E1A.x + E2A.x + E3A.x + HH.x)
                  + laA1 * (E1A.y + E2A.y + E3A.y + HH.y)
                  + laA2 * (E1A.z + E2A.z + E3A.z + HH.z)
                  + laA3 * (E1A.w + E2A.w + E3A.w + HH.w);
        // pair B
        const float laB0 = (1.0f - ALPHA) * (c0     == tgtB) + ALPHA * SMB.x;
        const float laB1 = (1.0f - ALPHA) * (c0 + 1 == tgtB) + ALPHA * SMB.y;
        const float laB2 = (1.0f - ALPHA) * (c0 + 2 == tgtB) + ALPHA * SMB.z;
        const float laB3 = (1.0f - ALPHA) * (c0 + 3 == tgtB) + ALPHA * SMB.w;
        float s1B = __expf(E1B.x) + __expf(E1B.y) + __expf(E1B.z) + __expf(E1B.w);
        float s2B = W2.x * __expf(E2B.x) + W2.y * __expf(E2B.y)
                  + W2.z * __expf(E2B.z) + W2.w * __expf(E2B.w);
        float s3B = W3.x * __expf(E3B.x) + W3.y * __expf(E3B.y)
                  + W3.z * __expf(E3B.z) + W3.w * __expf(E3B.w);
        float dtB = laB0 * (E1B.x + E2B.x + E3B.x + HH.x)
                  + laB1 * (E1B.y + E2B.y + E3B.y + HH.y)
                  + laB2 * (E1B.z + E2B.z + E3B.z + HH.z)
                  + laB3 * (E1B.w + E2B.w + E3B.w + HH.w);

        s1A = rowsum32(s1A);  s1B = rowsum32(s1B);
        s2A = rowsum32(s2A);  s2B = rowsum32(s2B);
        s3A = rowsum32(s3A);  s3B = rowsum32(s3B);
        dtA = rowsum32(dtA);  dtB = rowsum32(dtB);

        const float ceA = __logf(s1A * s2A * s3A) - dtA;
        const float ceB = __logf(s1B * s2B * s3B) - dtB;
        float lossAcc = own ? (ceA + ceB) : 0.f;
        const float lossW = __shfl(lossAcc, 16) + __shfl(lossAcc, 48);
        if (lane == 0) bl[wslot] = lossW;
        __syncthreads();
        if (threadIdx.x == 0)
            ploss[blockIdx.x] = bl[0] + bl[1] + bl[2] + bl[3];
    } else {
        // ================= KL role: old_pred,output -> kl partial + dout rows =================
        const int j  = blockIdx.x - HBLK;
        const int gw = j * 4 + wslot;
        const int rowA = 4 * gw + half;
        const int rowB = 4 * gw + 2 + half;
        const int tgtA = target[rowA];
        const int tgtB = target[rowB];
        const int baseA = rowA * C_N;
        const int baseB = rowB * C_N;

        float4 OPA, OUA, OPB, OUB;
        OPA = OUA = OPB = OUB = make_float4(NEG_SENT, NEG_SENT, NEG_SENT, NEG_SENT);
        if (act) {
            OPA = *(const float4*)(opp + baseA + c0);
            OPB = *(const float4*)(opp + baseB + c0);
            OUA = *(const float4*)(outp + baseA + c0);
            OUB = *(const float4*)(outp + baseB + c0);
        }
        const float rcA = 1.0f / (float)counts[tgtA];
        const float rcB = 1.0f / (float)counts[tgtB];

        // pair A
        const float aA0 = OPA.x * 0.5f, aA1 = OPA.y * 0.5f, aA2 = OPA.z * 0.5f, aA3 = OPA.w * 0.5f;
        const float pA0 = __expf(aA0), pA1 = __expf(aA1), pA2 = __expf(aA2), pA3 = __expf(aA3);
        float ztA = pA0 + pA1 + pA2 + pA3;
        float bvA = OPA.x; int biA = c0;
        if (OPA.y > bvA) { bvA = OPA.y; biA = c0 + 1; }
        if (OPA.z > bvA) { bvA = OPA.z; biA = c0 + 2; }
        if (OPA.w > bvA) { bvA = OPA.w; biA = c0 + 3; }
        unsigned bbA = __float_as_uint(bvA);
        bbA = ((int)bbA < 0) ? ~bbA : (bbA | 0x80000000u);
        unsigned khiA = bbA, kloA = (unsigned)~biA;
        const float esA0 = OUA.x * rcA, esA1 = OUA.y * rcA, esA2 = OUA.z * rcA, esA3 = OUA.w * rcA;
        const float xA0 = esA0 * 0.5f, xA1 = esA1 * 0.5f, xA2 = esA2 * 0.5f, xA3 = esA3 * 0.5f;
        float zsA = __expf(xA0) + __expf(xA1) + __expf(xA2) + __expf(xA3);
        float DA  = pA0 * (aA0 - xA0) + pA1 * (aA1 - xA1) + pA2 * (aA2 - xA2) + pA3 * (aA3 - xA3);
        if (act) {
            *(float2*)(dout + 2 + baseA + c0)     = make_float2(esA0, esA1);
            *(float2*)(dout + 2 + baseA + c0 + 2) = make_float2(esA2, esA3);
        }
        // pair B
        const float aB0 = OPB.x * 0.5f, aB1 = OPB.y * 0.5f, aB2 = OPB.z * 0.5f, aB3 = OPB.w * 0.5f;
        const float pB0 = __expf(aB0), pB1 = __expf(aB1), pB2 = __expf(aB2), pB3 = __expf(aB3);
        float ztB = pB0 + pB1 + pB2 + pB3;
        float bvB = OPB.x; int biB = c0;
        if (OPB.y > bvB) { bvB = OPB.y; biB = c0 + 1; }
        if (OPB.z > bvB) { bvB = OPB.z; biB = c0 + 2; }
        if (OPB.w > bvB) { bvB = OPB.w; biB = c0 + 3; }
        unsigned bbB = __float_as_uint(bvB);
        bbB = ((int)bbB < 0) ? ~bbB : (bbB | 0x80000000u);
        unsigned khiB = bbB, kloB = (unsigned)~biB;
        const float esB0 = OUB.x * rcB, esB1 = OUB.y * rcB, esB2 = OUB.z * rcB, esB3 = OUB.w * rcB;
        const float xB0 = esB0 * 0.5f, xB1 = esB1 * 0.5f, xB2 = esB2 * 0.5f, xB3 = esB3 * 0.5f;
        float zsB = __expf(xB0) + __expf(xB1) + __expf(xB2) + __expf(xB3);
        float DB  = pB0 * (aB0 - xB0) + pB1 * (aB1 - xB1) + pB2 * (aB2 - xB2) + pB3 * (aB3 - xB3);
        if (act) {
            *(float2*)(dout + 2 + baseB + c0)     = make_float2(esB0, esB1);
            *(float2*)(dout + 2 + baseB + c0 + 2) = make_float2(esB2, esB3);
        }

        ztA = rowsum32(ztA);  ztB = rowsum32(ztB);
        zsA = rowsum32(zsA);  zsB = rowsum32(zsB);
        DA  = rowsum32(DA);   DB  = rowsum32(DB);
        rowamax32(khiA, kloA);
        rowamax32(khiB, kloB);

        const int miA = (int)~kloA;
        const int miB = (int)~kloB;
        const float rztA = 1.0f / ztA, rztB = 1.0f / ztB;
        const float klvA = DA * rztA + __logf(zsA * rztA);
        const float klvB = DB * rztB + __logf(zsB * rztB);
        const bool selA = own && (miA == tgtA);
        const bool selB = own && (miB == tgtB);
        float klAcc = (selA ? klvA : 0.f) + (selB ? klvB : 0.f);
        float nAcc  = (selA ? 1.f : 0.f) + (selB ? 1.f : 0.f);
        const float klW = __shfl(klAcc, 16) + __shfl(klAcc, 48);
        const float nW  = __shfl(nAcc, 16) + __shfl(nAcc, 48);
        if (lane == 0) { bk[wslot] = klW; bn[wslot] = nW; }
        __syncthreads();
        if (threadIdx.x == 0) {
            pkl[j] = bk[0] + bk[1] + bk[2] + bk[3];
            pn[j]  = bn[0] + bn[1] + bn[2] + bn[3];
        }
    }
}

// ---------- final reduction ----------
__global__ void final_k(const float* __restrict__ ploss, const float* __restrict__ pkl,
                        const float* __restrict__ pn, float* __restrict__ dout) {
    __shared__ float sl[256], sk[256], sn[256];
    const int t = threadIdx.x;
    float l = 0.f, k = 0.f, n = 0.f;
    for (int i = t; i < HBLK; i += 256) { l += ploss[i]; k += pkl[i]; n += pn[i]; }
    sl[t] = l; sk[t] = k; sn[t] = n;
    __syncthreads();
    for (int s = 128; s; s >>= 1) {
        if (t < s) { sl[t] += sl[t + s]; sk[t] += sk[t + s]; sn[t] += sn[t + s]; }
        __syncthreads();
    }
    if (t == 0) {
        dout[0] = sl[0] / (float)B_N;
        const float kl = (sn[0] > 0.f) ? (sk[0] / fmaxf(sn[0], 1.f)) : 0.f;
        dout[1] = kl * (TEMP * TEMP) * 3.0f;
    }
}

extern "C" void kernel_launch(void* const* d_in, const int* in_sizes, int n_in,
                              void* d_out, int out_size, void* d_ws, size_t ws_size,
                              hipStream_t stream) {
    const int*   target = (const int*)  d_in[1];
    const float* cosf   = (const float*)d_in[2];
    const float* oldp   = (const float*)d_in[3];
    const float* e1     = (const float*)d_in[4];
    const float* e2     = (const float*)d_in[5];
    const float* e3     = (const float*)d_in[6];
    const float* outp   = (const float*)d_in[7];
    const float* prior  = (const float*)d_in[8];

    float* ws    = (float*)d_ws;
    float* sm    = ws;                  // [10000] (+16 pad)
    float* w2    = ws + 10016;          // [104]
    float* w3    = ws + 10120;          // [104]
    float* Ht    = ws + 10224;          // [104]
    int*   cnts  = (int*)(ws + 10328);  // [104]
    float* ploss = ws + 10432;          // [HBLK]
    float* pkl   = ploss + HBLK;        // [HBLK]
    float* pn    = pkl + HBLK;          // [HBLK]

    hipMemsetAsync(cnts, 0, C_N * sizeof(int), stream);
    prep_k<<<261, 256, 0, stream>>>(cosf, prior, target, sm, w2, w3, Ht, cnts);
    main_k<<<NBLK, 256, 0, stream>>>(target, e1, e2, e3, oldp, outp,
                                     sm, w2, w3, Ht, cnts, (float*)d_out, ploss, pkl, pn);
    final_k<<<1, 256, 0, stream>>>(ploss, pkl, pn, (float*)d_out);
}